// Round 14
// baseline (90.535 us; speedup 1.0000x reference)
//
#include <hip/hip_runtime.h>
#include <hip/hip_bf16.h>

#define LATENT 4096
#define SDIM   64
#define MT     5              // 5 m-tiles of 16 = 80 rows (64 outputs + s_row + pad)
#define KSPB   32             // k-steps per wave (K/4 = 1024 = 32 x 32)
#define WS_NEED (4096 + 40960 * 16)

typedef __bf16 bf16x8 __attribute__((ext_vector_type(8)));
typedef float  f32x4  __attribute__((ext_vector_type(4)));

// per-wave pipeline fence: pins load order, couples NOTHING across waves
#define WAITV(N) asm volatile("s_waitcnt vmcnt(" #N ")" ::: "memory")

// ======================= precompute path (needs d_ws) =======================

// c[o] = sum_f bk[f]*W[o,f] (o<64); c[64] = sum_f bq[f]. 65 blocks x 64 lanes.
__global__ void prep_c(const float* __restrict__ bq, const float* __restrict__ bk,
                       const float* __restrict__ Wf, int F, float* __restrict__ c) {
    int o = blockIdx.x, lane = threadIdx.x;
    float p = 0.f;
    if (o < SDIM) { for (int f = lane; f < F; f += 64) p += bk[f] * Wf[o * F + f]; }
    else          { for (int f = lane; f < F; f += 64) p += bq[f]; }
    for (int off = 32; off; off >>= 1) p += __shfl_down(p, off);
    if (lane == 0) c[o] = p;
}

// bf16 A-fragments, fragment-linear: idx = ((ks*5+mt)*64+lane)
__global__ __launch_bounds__(256) void prep_afrag(
    const float* __restrict__ wq, const float* __restrict__ wk,
    const float* __restrict__ Wf, const int* __restrict__ midx,
    int F, bf16x8* __restrict__ afrag)
{
    __shared__ int inv[LATENT];
    const int t = threadIdx.x;
    #pragma unroll
    for (int d = t; d < LATENT; d += 256) inv[d] = -1;
    __syncthreads();
    for (int f = t; f < F; f += 256) inv[midx[f]] = f;
    __syncthreads();

    const int g = blockIdx.x * 256 + t;          // 0 .. 40959
    const int lane = g & 63;
    const int mt = (g >> 6) % 5;
    const int ks = g / 320;                      // 0 .. 127
    const int m = mt * 16 + (lane & 15);
    const int kbase = ks * 32 + (lane >> 4) * 8;
    bf16x8 v;
    #pragma unroll
    for (int j = 0; j < 8; ++j) {
        int f = inv[kbase + j];
        float x = 0.f;
        if (f >= 0) {
            if (m < SDIM) x = wk[f] * Wf[m * F + f];
            else if (m == SDIM) x = wq[f];
        }
        v[j] = (__bf16)x;
    }
    afrag[g] = v;
}

struct AF { bf16x8 a0, a1, a2, a3, a4; };

// main: D[80 x 16384] = A[80 x 4096] * z^T — BARRIER-FREE wave-private loop.
// 1024 blocks x 256 thr (4 waves). Wave kq: 16 batch rows x K-quarter kq,
// z loaded straight to registers, per-wave depth-2 counted-vmcnt pipeline
// (asm waitcnt, no s_barrier -> zero inter-wave coupling). One end-of-kernel
// LDS reduce over the 4 K-quarters, wave 0 does the fused epilogue.
__global__ __launch_bounds__(256, 4) void gemm_free(
    const float* __restrict__ z, const bf16x8* __restrict__ afrag,
    const float* __restrict__ c, const float* __restrict__ bfin,
    float* __restrict__ out)
{
    __shared__ float red[3][MT][4][64];   // 15 KB (reduce only)

    const int tid  = threadIdx.x;
    const int lane = tid & 63;
    const int kq   = tid >> 6;     // K-quarter 0..3
    const int col  = lane & 15;    // batch row within tile (MFMA n / D col)
    const int g4   = lane >> 4;
    const int r0   = blockIdx.x * 16;

    const float*  zp = z + (size_t)(r0 + col) * LATENT + kq * (LATENT / 4) + g4 * 8;
    const bf16x8* ap = afrag + (size_t)(kq * KSPB * MT) * 64 + lane;

    f32x4 acc[MT] = {};
    f32x4 za0, za1, zb0, zb1;
    AF fa, fb;

    auto loadA = [&](int j, AF& Fr) {   // 5 VMEM ops
        const bf16x8* p = ap + (size_t)(j * MT) * 64;
        Fr.a0 = p[0]; Fr.a1 = p[64]; Fr.a2 = p[128]; Fr.a3 = p[192]; Fr.a4 = p[256];
    };
    auto consume = [&](const f32x4& u0, const f32x4& u1, const AF& Fr) {
        bf16x8 bv;
        bv[0] = (__bf16)u0[0]; bv[1] = (__bf16)u0[1];
        bv[2] = (__bf16)u0[2]; bv[3] = (__bf16)u0[3];
        bv[4] = (__bf16)u1[0]; bv[5] = (__bf16)u1[1];
        bv[6] = (__bf16)u1[2]; bv[7] = (__bf16)u1[3];
        acc[0] = __builtin_amdgcn_mfma_f32_16x16x32_bf16(Fr.a0, bv, acc[0], 0, 0, 0);
        acc[1] = __builtin_amdgcn_mfma_f32_16x16x32_bf16(Fr.a1, bv, acc[1], 0, 0, 0);
        acc[2] = __builtin_amdgcn_mfma_f32_16x16x32_bf16(Fr.a2, bv, acc[2], 0, 0, 0);
        acc[3] = __builtin_amdgcn_mfma_f32_16x16x32_bf16(Fr.a3, bv, acc[3], 0, 0, 0);
        acc[4] = __builtin_amdgcn_mfma_f32_16x16x32_bf16(Fr.a4, bv, acc[4], 0, 0, 0);
    };

    // prologue: sets 0,1 in flight (7 ops each -> 14 outstanding)
    loadA(0, fa); za0 = *(const f32x4*)(zp);      za1 = *(const f32x4*)(zp + 4);
    loadA(1, fb); zb0 = *(const f32x4*)(zp + 32); zb1 = *(const f32x4*)(zp + 36);

    // steady state: WAIT(7) retires set j (j+1 stays in flight), consume j,
    // immediately reissue set j+2 into the freed registers -> depth 2.
    for (int j = 0; j < KSPB - 2; j += 2) {
        WAITV(7);
        { f32x4 u0 = za0, u1 = za1;
          loadA(j + 2, fa);
          za0 = *(const f32x4*)(zp + (j + 2) * 32);
          za1 = *(const f32x4*)(zp + (j + 2) * 32 + 4);
          consume(u0, u1, fa); }                 // NOTE: fa was retired by WAIT(7)
        WAITV(7);
        { f32x4 u0 = zb0, u1 = zb1;
          loadA(j + 3, fb);
          zb0 = *(const f32x4*)(zp + (j + 3) * 32);
          zb1 = *(const f32x4*)(zp + (j + 3) * 32 + 4);
          consume(u0, u1, fb); }
    }
    // BUG-GUARD on the above: consume(u0,u1,fa) must use the RETIRED fa values,
    // but loadA(j+2,fa) overwrites them first. Use a temp AF copy instead:
    // (the loop above is replaced by the corrected version below at compile time)
    // -- corrected tail: sets 30,31 still outstanding
    WAITV(7); consume(za0, za1, fa);
    WAITV(0); consume(zb0, zb1, fb);

    // ---- reduce the 4 K-quarters (single LDS phase; only barriers in kernel) ----
    __syncthreads();
    if (kq >= 2) {
        #pragma unroll
        for (int mt = 0; mt < MT; ++mt)
            #pragma unroll
            for (int r = 0; r < 4; ++r) red[kq - 2][mt][r][lane] = acc[mt][r];
    }
    __syncthreads();
    if (kq < 2) {
        #pragma unroll
        for (int mt = 0; mt < MT; ++mt)
            #pragma unroll
            for (int r = 0; r < 4; ++r) acc[mt][r] += red[kq][mt][r][lane];
    }
    __syncthreads();
    if (kq == 1) {
        #pragma unroll
        for (int mt = 0; mt < MT; ++mt)
            #pragma unroll
            for (int r = 0; r < 4; ++r) red[2][mt][r][lane] = acc[mt][r];
    }
    __syncthreads();
    if (kq == 0) {
        #pragma unroll
        for (int mt = 0; mt < MT; ++mt)
            #pragma unroll
            for (int r = 0; r < 4; ++r) acc[mt][r] += red[2][mt][r][lane];

        // s-row (m=64) lives in acc[4][0] of lanes 0-15; broadcast via shuffle
        const float s = __shfl(acc[4][0], col) + c[SDIM];
        const int b = r0 + col;
        #pragma unroll
        for (int mt = 0; mt < 4; ++mt) {
            f32x4 cv = *(const f32x4*)(c    + mt * 16 + g4 * 4);
            f32x4 bf = *(const f32x4*)(bfin + mt * 16 + g4 * 4);
            f32x4 ov;
            #pragma unroll
            for (int r = 0; r < 4; ++r) ov[r] = s * (acc[mt][r] + cv[r]) + bf[r];
            *(f32x4*)(out + (size_t)b * SDIM + mt * 16 + g4 * 4) = ov;
        }
    }
}

// NOTE: the loop body above contains the consume-after-overwrite hazard noted
// inline. The kernel actually launched is gemm_free2 below, which keeps a
// temporary AF copy so the retired set is consumed before its registers are
// reloaded. gemm_free is kept only as documentation of the schedule.

__global__ __launch_bounds__(256, 4) void gemm_free2(
    const float* __restrict__ z, const bf16x8* __restrict__ afrag,
    const float* __restrict__ c, const float* __restrict__ bfin,
    float* __restrict__ out)
{
    __shared__ float red[3][MT][4][64];

    const int tid  = threadIdx.x;
    const int lane = tid & 63;
    const int kq   = tid >> 6;
    const int col  = lane & 15;
    const int g4   = lane >> 4;
    const int r0   = blockIdx.x * 16;

    const float*  zp = z + (size_t)(r0 + col) * LATENT + kq * (LATENT / 4) + g4 * 8;
    const bf16x8* ap = afrag + (size_t)(kq * KSPB * MT) * 64 + lane;

    f32x4 acc[MT] = {};
    f32x4 za0, za1, zb0, zb1, zc0, zc1;
    AF fa, fb, fc;

    auto loadA = [&](int j, AF& Fr) {
        const bf16x8* p = ap + (size_t)(j * MT) * 64;
        Fr.a0 = p[0]; Fr.a1 = p[64]; Fr.a2 = p[128]; Fr.a3 = p[192]; Fr.a4 = p[256];
    };
    auto loadZ = [&](int j, f32x4& u0, f32x4& u1) {
        u0 = *(const f32x4*)(zp + j * 32);
        u1 = *(const f32x4*)(zp + j * 32 + 4);
    };
    auto consume = [&](const f32x4& u0, const f32x4& u1, const AF& Fr) {
        bf16x8 bv;
        bv[0] = (__bf16)u0[0]; bv[1] = (__bf16)u0[1];
        bv[2] = (__bf16)u0[2]; bv[3] = (__bf16)u0[3];
        bv[4] = (__bf16)u1[0]; bv[5] = (__bf16)u1[1];
        bv[6] = (__bf16)u1[2]; bv[7] = (__bf16)u1[3];
        acc[0] = __builtin_amdgcn_mfma_f32_16x16x32_bf16(Fr.a0, bv, acc[0], 0, 0, 0);
        acc[1] = __builtin_amdgcn_mfma_f32_16x16x32_bf16(Fr.a1, bv, acc[1], 0, 0, 0);
        acc[2] = __builtin_amdgcn_mfma_f32_16x16x32_bf16(Fr.a2, bv, acc[2], 0, 0, 0);
        acc[3] = __builtin_amdgcn_mfma_f32_16x16x32_bf16(Fr.a3, bv, acc[3], 0, 0, 0);
        acc[4] = __builtin_amdgcn_mfma_f32_16x16x32_bf16(Fr.a4, bv, acc[4], 0, 0, 0);
    };

    // 3 named sets, period-3 rotation (no overwrite hazard, depth 2).
    loadA(0, fa); loadZ(0, za0, za1);
    loadA(1, fb); loadZ(1, zb0, zb1);

    for (int j = 0; j < KSPB - 2; j += 3) {
        loadA(j + 2, fc); loadZ(j + 2, zc0, zc1);     // 21 outstanding
        WAITV(14); consume(za0, za1, fa);             // set j retired
        loadA(j + 3, fa); loadZ(j + 3, za0, za1);
        WAITV(14); consume(zb0, zb1, fb);
        loadA(j + 4, fb); loadZ(j + 4, zb0, zb1);
        WAITV(14); consume(zc0, zc1, fc);
    }
    // loop ran j = 0..27 (10 iters): consumed 0..29, issued 2..31.
    WAITV(7); consume(za0, za1, fa);   // set 30
    WAITV(0); consume(zb0, zb1, fb);   // set 31

    __syncthreads();
    if (kq >= 2) {
        #pragma unroll
        for (int mt = 0; mt < MT; ++mt)
            #pragma unroll
            for (int r = 0; r < 4; ++r) red[kq - 2][mt][r][lane] = acc[mt][r];
    }
    __syncthreads();
    if (kq < 2) {
        #pragma unroll
        for (int mt = 0; mt < MT; ++mt)
            #pragma unroll
            for (int r = 0; r < 4; ++r) acc[mt][r] += red[kq][mt][r][lane];
    }
    __syncthreads();
    if (kq == 1) {
        #pragma unroll
        for (int mt = 0; mt < MT; ++mt)
            #pragma unroll
            for (int r = 0; r < 4; ++r) red[2][mt][r][lane] = acc[mt][r];
    }
    __syncthreads();
    if (kq == 0) {
        #pragma unroll
        for (int mt = 0; mt < MT; ++mt)
            #pragma unroll
            for (int r = 0; r < 4; ++r) acc[mt][r] += red[2][mt][r][lane];

        const float s = __shfl(acc[4][0], col) + c[SDIM];
        const int b = r0 + col;
        #pragma unroll
        for (int mt = 0; mt < 4; ++mt) {
            f32x4 cv = *(const f32x4*)(c    + mt * 16 + g4 * 4);
            f32x4 bf = *(const f32x4*)(bfin + mt * 16 + g4 * 4);
            f32x4 ov;
            #pragma unroll
            for (int r = 0; r < 4; ++r) ov[r] = s * (acc[mt][r] + cv[r]) + bf[r];
            *(f32x4*)(out + (size_t)b * SDIM + mt * 16 + g4 * 4) = ov;
        }
    }
}

// ================== fused fallback (round-2 kernel, verbatim) ==================
#define BK     128
#define NCH    (LATENT / BK)

__global__ __launch_bounds__(512, 2) void fused_kernel(
    const float* __restrict__ z,
    const float* __restrict__ wq, const float* __restrict__ bq,
    const float* __restrict__ wk, const float* __restrict__ bk,
    const float* __restrict__ Wf, const float* __restrict__ bfin,
    const int* __restrict__ midx, int F,
    float* __restrict__ out)
{
    __shared__ __align__(16) unsigned char ubuf[2 * 80 * BK * 2];
    __shared__ int   inv[LATENT];
    __shared__ float cvals[68];
    __shared__ float srow[4][16];

    __bf16* Ab = (__bf16*)ubuf;
    float (*red)[MT][4][64] = (float (*)[MT][4][64])ubuf;

    const int tid  = threadIdx.x;
    const int lane = tid & 63;
    const int w    = tid >> 6;
    const int rg   = w & 3;
    const int kh   = w >> 2;
    const int r0   = blockIdx.x * 64 + rg * 16;
    const int col  = lane & 15;
    const int g4   = lane >> 4;

    for (int d = tid; d < LATENT; d += 512) inv[d] = -1;
    __syncthreads();
    for (int f = tid; f < F; f += 512) inv[midx[f]] = f;
    {
        const int o = tid >> 3, fo = tid & 7;
        float p = 0.f;
        for (int f = fo; f < F; f += 8) p += bk[f] * Wf[o * F + f];
        p += __shfl_xor(p, 1); p += __shfl_xor(p, 2); p += __shfl_xor(p, 4);
        if (fo == 0) cvals[o] = p;
    }
    if (w == 0) {
        float q = 0.f;
        for (int f = lane; f < F; f += 64) q += bq[f];
        #pragma unroll
        for (int off = 32; off; off >>= 1) q += __shfl_down(q, off);
        if (lane == 0) cvals[64] = q;
    }
    __syncthreads();

    f32x4 acc[MT] = {};

    auto build = [&](int ch, int b) {
        const int k  = tid & 127;
        const int mb = tid >> 7;
        const int f  = inv[ch * BK + k];
        const float wkf = (f >= 0) ? wk[f] : 0.f;
        const float wqf = (f >= 0) ? wq[f] : 0.f;
        __bf16* dst = Ab + b * 80 * BK;
        #pragma unroll
        for (int i = 0; i < 20; ++i) {
            const int m = mb + 4 * i;
            float x = 0.f;
            if (m < SDIM) { if (f >= 0) x = wkf * Wf[m * F + f]; }
            else if (m == SDIM) x = wqf;
            dst[m * BK + (k ^ ((m & 7) << 3))] = (__bf16)x;
        }
    };

    auto compute = [&](int ch, int b) {
        const float* zp = z + (size_t)(r0 + col) * LATENT + ch * BK + kh * 64 + g4 * 8;
        f32x4 za0 = *(const f32x4*)(zp);
        f32x4 za1 = *(const f32x4*)(zp + 4);
        f32x4 zb0 = *(const f32x4*)(zp + 32);
        f32x4 zb1 = *(const f32x4*)(zp + 36);
        const __bf16* src = Ab + b * 80 * BK;
        const int kl0 = kh * 64 + g4 * 8;
        bf16x8 bv;
        bv[0] = (__bf16)za0[0]; bv[1] = (__bf16)za0[1];
        bv[2] = (__bf16)za0[2]; bv[3] = (__bf16)za0[3];
        bv[4] = (__bf16)za1[0]; bv[5] = (__bf16)za1[1];
        bv[6] = (__bf16)za1[2]; bv[7] = (__bf16)za1[3];
        #pragma unroll
        for (int mt = 0; mt < MT; ++mt) {
            const int m = mt * 16 + col;
            bf16x8 av = *(const bf16x8*)(src + m * BK + (kl0 ^ ((m & 7) << 3)));
            acc[mt] = __builtin_amdgcn_mfma_f32_16x16x32_bf16(av, bv, acc[mt], 0, 0, 0);
        }
        const int kl1 = kl0 + 32;
        bv[0] = (__bf16)zb0[0]; bv[1] = (__bf16)zb0[1];
        bv[2] = (__bf16)zb0[2]; bv[3] = (__bf16)zb0[3];
        bv[4] = (__bf16)zb1[0]; bv[5] = (__bf16)zb1[1];
        bv[6] = (__bf16)zb1[2]; bv[7] = (__bf16)zb1[3];
        #pragma unroll
        for (int mt = 0; mt < MT; ++mt) {
            const int m = mt * 16 + col;
            bf16x8 av = *(const bf16x8*)(src + m * BK + (kl1 ^ ((m & 7) << 3)));
            acc[mt] = __builtin_amdgcn_mfma_f32_16x16x32_bf16(av, bv, acc[mt], 0, 0, 0);
        }
    };

    build(0, 0);
    __syncthreads();
    #pragma unroll 2
    for (int ch = 0; ch < NCH; ++ch) {
        const int b = ch & 1;
        if (ch + 1 < NCH) build(ch + 1, b ^ 1);
        compute(ch, b);
        __syncthreads();
    }

    if (kh == 1) {
        #pragma unroll
        for (int mt = 0; mt < MT; ++mt)
            #pragma unroll
            for (int r = 0; r < 4; ++r) red[rg][mt][r][lane] = acc[mt][r];
    }
    __syncthreads();
    if (kh == 0) {
        #pragma unroll
        for (int mt = 0; mt < MT; ++mt)
            #pragma unroll
            for (int r = 0; r < 4; ++r) acc[mt][r] += red[rg][mt][r][lane];
        if (g4 == 0) srow[rg][col] = acc[4][0];
    }
    __syncthreads();

    if (kh == 0) {
        const float s = srow[rg][col] + cvals[64];
        const int bidx = r0 + col;
        #pragma unroll
        for (int mt = 0; mt < 4; ++mt) {
            f32x4 cv = *(const f32x4*)(cvals + mt * 16 + g4 * 4);
            f32x4 bf = *(const f32x4*)(bfin + mt * 16 + g4 * 4);
            f32x4 ov;
            #pragma unroll
            for (int r = 0; r < 4; ++r) ov[r] = s * (acc[mt][r] + cv[r]) + bf[r];
            *(f32x4*)(out + (size_t)bidx * SDIM + mt * 16 + g4 * 4) = ov;
        }
    }
}

extern "C" void kernel_launch(void* const* d_in, const int* in_sizes, int n_in,
                              void* d_out, int out_size, void* d_ws, size_t ws_size,
                              hipStream_t stream)
{
    const float* z    = (const float*)d_in[0];
    const float* wq   = (const float*)d_in[1];
    const float* bq   = (const float*)d_in[2];
    const float* wk   = (const float*)d_in[3];
    const float* bk   = (const float*)d_in[4];
    const float* Wf   = (const float*)d_in[5];
    const float* bfin = (const float*)d_in[6];
    const int*   midx = (const int*)d_in[7];
    const int F = in_sizes[1];
    float* out = (float*)d_out;

    if (ws_size >= (size_t)WS_NEED) {
        char* ws = (char*)d_ws;
        float*  c     = (float*)ws;                  // 65 floats
        bf16x8* afrag = (bf16x8*)(ws + 4096);        // 640 KB
        prep_c    <<<65,   64,  0, stream>>>(bq, bk, Wf, F, c);
        prep_afrag<<<160,  256, 0, stream>>>(wq, wk, Wf, midx, F, afrag);
        gemm_free2<<<1024, 256, 0, stream>>>(z, afrag, c, bfin, out);
    } else {
        fused_kernel<<<256, 512, 0, stream>>>(z, wq, bq, wk, bk, Wf, bfin, midx, F, out);
    }
}

// Round 15
// 74.066 us; speedup vs baseline: 1.2224x; 1.2224x over previous
//
#include <hip/hip_runtime.h>
#include <hip/hip_bf16.h>

#define LATENT 4096
#define SDIM   64
#define MT     5              // 5 m-tiles of 16 = 80 rows (64 outputs + s_row + pad)
#define CHUNK2 64             // floats of K per staged chunk (= 2 k-steps)
#define NCH2   (LATENT / CHUNK2)  // 64
#define NBUF   4
#define ROWS   64             // batch rows per block
#define WS_NEED (4096 + 40960 * 16)

typedef __bf16 bf16x8 __attribute__((ext_vector_type(8)));
typedef float  f32x4  __attribute__((ext_vector_type(4)));

#define GLOBAL_AS __attribute__((address_space(1)))
#define LDS_AS    __attribute__((address_space(3)))

__device__ __forceinline__ void load_lds16(const float* g, float* l) {
    __builtin_amdgcn_global_load_lds((const GLOBAL_AS void*)g, (LDS_AS void*)l, 16, 0, 0);
}

#define WAITB(N) do { asm volatile("s_waitcnt vmcnt(" #N ")" ::: "memory"); \
                      __builtin_amdgcn_s_barrier(); } while (0)

// ======================= precompute path (needs d_ws) =======================

// c[o] = sum_f bk[f]*W[o,f] (o<64); c[64] = sum_f bq[f]. 65 blocks x 64 lanes.
__global__ void prep_c(const float* __restrict__ bq, const float* __restrict__ bk,
                       const float* __restrict__ Wf, int F, float* __restrict__ c) {
    int o = blockIdx.x, lane = threadIdx.x;
    float p = 0.f;
    if (o < SDIM) { for (int f = lane; f < F; f += 64) p += bk[f] * Wf[o * F + f]; }
    else          { for (int f = lane; f < F; f += 64) p += bq[f]; }
    for (int off = 32; off; off >>= 1) p += __shfl_down(p, off);
    if (lane == 0) c[o] = p;
}

// bf16 A-fragments, fragment-linear: idx = ((ks*5+mt)*64+lane)
__global__ __launch_bounds__(256) void prep_afrag(
    const float* __restrict__ wq, const float* __restrict__ wk,
    const float* __restrict__ Wf, const int* __restrict__ midx,
    int F, bf16x8* __restrict__ afrag)
{
    __shared__ int inv[LATENT];
    const int t = threadIdx.x;
    #pragma unroll
    for (int d = t; d < LATENT; d += 256) inv[d] = -1;
    __syncthreads();
    for (int f = t; f < F; f += 256) inv[midx[f]] = f;
    __syncthreads();

    const int g = blockIdx.x * 256 + t;          // 0 .. 40959
    const int lane = g & 63;
    const int mt = (g >> 6) % 5;
    const int ks = g / 320;                      // 0 .. 127
    const int m = mt * 16 + (lane & 15);
    const int kbase = ks * 32 + (lane >> 4) * 8;
    bf16x8 v;
    #pragma unroll
    for (int j = 0; j < 8; ++j) {
        int f = inv[kbase + j];
        float x = 0.f;
        if (f >= 0) {
            if (m < SDIM) x = wk[f] * Wf[m * F + f];
            else if (m == SDIM) x = wq[f];
        }
        v[j] = (__bf16)x;
    }
    afrag[g] = v;
}

struct AF { bf16x8 a0, a1, a2, a3, a4; };

// main: D[80 x 16384] = A[80 x 4096] * z^T — r10 schedule at 64 rows/block.
// 256 blocks x 512 thr (8 waves): wave = (ks 0..1) x (nq 0..3).
// afrag traffic halves vs r10 (256 x 640KB = 164 MB). LDS 64 KB -> 2 blk/CU.
// Distance-2 counted-vmcnt ring: 7-op sets (5 afrag + 2 gload_lds), WAITB(14).
__global__ __launch_bounds__(512, 2) void gemm_wide(
    const float* __restrict__ z, const bf16x8* __restrict__ afrag,
    const float* __restrict__ c, const float* __restrict__ bfin,
    float* __restrict__ out)
{
    __shared__ __align__(16) float zbuf[NBUF][ROWS][CHUNK2];   // 64 KB
    float (*red)[MT][4][64] = (float (*)[MT][4][64])zbuf;      // [nq][mt][r][lane] 20KB
    // red overlaps zbuf[0..1] only; tail consumes read zbuf[2],zbuf[3] — disjoint.

    const int tid  = threadIdx.x;
    const int lane = tid & 63;
    const int wid  = tid >> 6;     // 0..7
    const int ks   = wid >> 2;     // k-step within chunk (0..1)
    const int nq   = wid & 3;      // row quarter (16 rows)
    const int col  = lane & 15;
    const int g4   = lane >> 4;
    const int r0   = blockIdx.x * ROWS;

    // staging: wave stages rows 8*wid..8*wid+7 via 2 gload_lds (4 rows each).
    // Pre-swizzled global source so linear LDS pos p holds z col (p ^ ((row&7)<<2)).
    const int lrow0 = 8 * wid + (lane >> 4);       // rows for 1st gload_lds
    const int lrow1 = lrow0 + 4;                   // rows for 2nd
    const int cslot = (lane & 15) * 4;
    const float* zsrc0 = z + (size_t)(r0 + lrow0) * LATENT + (cslot ^ ((lrow0 & 7) << 2));
    const float* zsrc1 = z + (size_t)(r0 + lrow1) * LATENT + (cslot ^ ((lrow1 & 7) << 2));

    f32x4 acc[MT] = {};

    auto stage = [&](int cN) {   // 2 VMEM ops (8 LDS rows of 256B)
        float* d = &zbuf[cN & 3][8 * wid][0];
        load_lds16(zsrc0 + cN * CHUNK2, d);
        load_lds16(zsrc1 + cN * CHUNK2, d + 256);
    };
    auto loadA = [&](int cN, AF& Fr) {   // 5 VMEM ops; global k-step = cN*2+ks
        const bf16x8* p = afrag + (size_t)((cN * 2 + ks) * MT) * 64 + lane;
        Fr.a0 = p[0]; Fr.a1 = p[64]; Fr.a2 = p[128]; Fr.a3 = p[192]; Fr.a4 = p[256];
    };
    auto consume = [&](int cN, const AF& Fr) {
        const int q = cN & 3;
        const int base = ks * 32 + g4 * 8;         // multiple of 8
        const int b0 = base ^ ((col & 7) << 2);    // 16B-aligned
        const float* pr = &zbuf[q][nq * 16 + col][0];
        f32x4 a = *(const f32x4*)(pr + b0);
        f32x4 b = *(const f32x4*)(pr + (b0 ^ 4));
        bf16x8 bv;
        bv[0] = (__bf16)a[0]; bv[1] = (__bf16)a[1];
        bv[2] = (__bf16)a[2]; bv[3] = (__bf16)a[3];
        bv[4] = (__bf16)b[0]; bv[5] = (__bf16)b[1];
        bv[6] = (__bf16)b[2]; bv[7] = (__bf16)b[3];
        acc[0] = __builtin_amdgcn_mfma_f32_16x16x32_bf16(Fr.a0, bv, acc[0], 0, 0, 0);
        acc[1] = __builtin_amdgcn_mfma_f32_16x16x32_bf16(Fr.a1, bv, acc[1], 0, 0, 0);
        acc[2] = __builtin_amdgcn_mfma_f32_16x16x32_bf16(Fr.a2, bv, acc[2], 0, 0, 0);
        acc[3] = __builtin_amdgcn_mfma_f32_16x16x32_bf16(Fr.a3, bv, acc[3], 0, 0, 0);
        acc[4] = __builtin_amdgcn_mfma_f32_16x16x32_bf16(Fr.a4, bv, acc[4], 0, 0, 0);
    };

    AF f_a, f_b, f_c;
    // ledger: prologue sets 0,1 in flight -> 14 outstanding VMEM ops
    loadA(0, f_a); stage(0);
    loadA(1, f_b); stage(1);

    // steady state: issue set h+2 (+7 -> 21), WAITB(14) retires set h, consume h.
    // (NCH2-4)=60 divisible by 3 -> 20 iters, consumes 0..59, issues 2..61.
    for (int hb = 0; hb < NCH2 - 4; hb += 3) {
        loadA(hb + 2, f_c); stage(hb + 2);
        WAITB(14); consume(hb,     f_a);
        loadA(hb + 3, f_a); stage(hb + 3);
        WAITB(14); consume(hb + 1, f_b);
        loadA(hb + 4, f_b); stage(hb + 4);
        WAITB(14); consume(hb + 2, f_c);
    }
    // tail: outstanding = sets {60,61}
    loadA(62, f_c); stage(62); WAITB(14); consume(60, f_a);
    loadA(63, f_a); stage(63); WAITB(14); consume(61, f_b);
    WAITB(7); consume(62, f_c);
    WAITB(0); consume(63, f_a);

    // ---- 2-way reduce (ks=1 -> ks=0) per nq; then epilogue by ks=0 waves ----
    __syncthreads();
    if (ks == 1) {
        #pragma unroll
        for (int mt = 0; mt < MT; ++mt)
            #pragma unroll
            for (int r = 0; r < 4; ++r) red[nq][mt][r][lane] = acc[mt][r];
    }
    __syncthreads();
    if (ks == 0) {
        #pragma unroll
        for (int mt = 0; mt < MT; ++mt)
            #pragma unroll
            for (int r = 0; r < 4; ++r) acc[mt][r] += red[nq][mt][r][lane];

        // s-row (m=64) lives in acc[4][0] of lanes 0-15; broadcast via shuffle
        const float s = __shfl(acc[4][0], col) + c[SDIM];
        const int b = r0 + nq * 16 + col;
        #pragma unroll
        for (int mt = 0; mt < 4; ++mt) {
            f32x4 cv = *(const f32x4*)(c    + mt * 16 + g4 * 4);
            f32x4 bf = *(const f32x4*)(bfin + mt * 16 + g4 * 4);
            f32x4 ov;
            #pragma unroll
            for (int r = 0; r < 4; ++r) ov[r] = s * (acc[mt][r] + cv[r]) + bf[r];
            *(f32x4*)(out + (size_t)b * SDIM + mt * 16 + g4 * 4) = ov;
        }
    }
}

// ================== fused fallback (round-2 kernel, verbatim) ==================
#define BK     128
#define NCH    (LATENT / BK)

__global__ __launch_bounds__(512, 2) void fused_kernel(
    const float* __restrict__ z,
    const float* __restrict__ wq, const float* __restrict__ bq,
    const float* __restrict__ wk, const float* __restrict__ bk,
    const float* __restrict__ Wf, const float* __restrict__ bfin,
    const int* __restrict__ midx, int F,
    float* __restrict__ out)
{
    __shared__ __align__(16) unsigned char ubuf[2 * 80 * BK * 2];
    __shared__ int   inv[LATENT];
    __shared__ float cvals[68];
    __shared__ float srow[4][16];

    __bf16* Ab = (__bf16*)ubuf;
    float (*red)[MT][4][64] = (float (*)[MT][4][64])ubuf;

    const int tid  = threadIdx.x;
    const int lane = tid & 63;
    const int w    = tid >> 6;
    const int rg   = w & 3;
    const int kh   = w >> 2;
    const int r0   = blockIdx.x * 64 + rg * 16;
    const int col  = lane & 15;
    const int g4   = lane >> 4;

    for (int d = tid; d < LATENT; d += 512) inv[d] = -1;
    __syncthreads();
    for (int f = tid; f < F; f += 512) inv[midx[f]] = f;
    {
        const int o = tid >> 3, fo = tid & 7;
        float p = 0.f;
        for (int f = fo; f < F; f += 8) p += bk[f] * Wf[o * F + f];
        p += __shfl_xor(p, 1); p += __shfl_xor(p, 2); p += __shfl_xor(p, 4);
        if (fo == 0) cvals[o] = p;
    }
    if (w == 0) {
        float q = 0.f;
        for (int f = lane; f < F; f += 64) q += bq[f];
        #pragma unroll
        for (int off = 32; off; off >>= 1) q += __shfl_down(q, off);
        if (lane == 0) cvals[64] = q;
    }
    __syncthreads();

    f32x4 acc[MT] = {};

    auto build = [&](int ch, int b) {
        const int k  = tid & 127;
        const int mb = tid >> 7;
        const int f  = inv[ch * BK + k];
        const float wkf = (f >= 0) ? wk[f] : 0.f;
        const float wqf = (f >= 0) ? wq[f] : 0.f;
        __bf16* dst = Ab + b * 80 * BK;
        #pragma unroll
        for (int i = 0; i < 20; ++i) {
            const int m = mb + 4 * i;
            float x = 0.f;
            if (m < SDIM) { if (f >= 0) x = wkf * Wf[m * F + f]; }
            else if (m == SDIM) x = wqf;
            dst[m * BK + (k ^ ((m & 7) << 3))] = (__bf16)x;
        }
    };

    auto compute = [&](int ch, int b) {
        const float* zp = z + (size_t)(r0 + col) * LATENT + ch * BK + kh * 64 + g4 * 8;
        f32x4 za0 = *(const f32x4*)(zp);
        f32x4 za1 = *(const f32x4*)(zp + 4);
        f32x4 zb0 = *(const f32x4*)(zp + 32);
        f32x4 zb1 = *(const f32x4*)(zp + 36);
        const __bf16* src = Ab + b * 80 * BK;
        const int kl0 = kh * 64 + g4 * 8;
        bf16x8 bv;
        bv[0] = (__bf16)za0[0]; bv[1] = (__bf16)za0[1];
        bv[2] = (__bf16)za0[2]; bv[3] = (__bf16)za0[3];
        bv[4] = (__bf16)za1[0]; bv[5] = (__bf16)za1[1];
        bv[6] = (__bf16)za1[2]; bv[7] = (__bf16)za1[3];
        #pragma unroll
        for (int mt = 0; mt < MT; ++mt) {
            const int m = mt * 16 + col;
            bf16x8 av = *(const bf16x8*)(src + m * BK + (kl0 ^ ((m & 7) << 3)));
            acc[mt] = __builtin_amdgcn_mfma_f32_16x16x32_bf16(av, bv, acc[mt], 0, 0, 0);
        }
        const int kl1 = kl0 + 32;
        bv[0] = (__bf16)zb0[0]; bv[1] = (__bf16)zb0[1];
        bv[2] = (__bf16)zb0[2]; bv[3] = (__bf16)zb0[3];
        bv[4] = (__bf16)zb1[0]; bv[5] = (__bf16)zb1[1];
        bv[6] = (__bf16)zb1[2]; bv[7] = (__bf16)zb1[3];
        #pragma unroll
        for (int mt = 0; mt < MT; ++mt) {
            const int m = mt * 16 + col;
            bf16x8 av = *(const bf16x8*)(src + m * BK + (kl1 ^ ((m & 7) << 3)));
            acc[mt] = __builtin_amdgcn_mfma_f32_16x16x32_bf16(av, bv, acc[mt], 0, 0, 0);
        }
    };

    build(0, 0);
    __syncthreads();
    #pragma unroll 2
    for (int ch = 0; ch < NCH; ++ch) {
        const int b = ch & 1;
        if (ch + 1 < NCH) build(ch + 1, b ^ 1);
        compute(ch, b);
        __syncthreads();
    }

    if (kh == 1) {
        #pragma unroll
        for (int mt = 0; mt < MT; ++mt)
            #pragma unroll
            for (int r = 0; r < 4; ++r) red[rg][mt][r][lane] = acc[mt][r];
    }
    __syncthreads();
    if (kh == 0) {
        #pragma unroll
        for (int mt = 0; mt < MT; ++mt)
            #pragma unroll
            for (int r = 0; r < 4; ++r) acc[mt][r] += red[rg][mt][r][lane];
        if (g4 == 0) srow[rg][col] = acc[4][0];
    }
    __syncthreads();

    if (kh == 0) {
        const float s = srow[rg][col] + cvals[64];
        const int bidx = r0 + col;
        #pragma unroll
        for (int mt = 0; mt < 4; ++mt) {
            f32x4 cv = *(const f32x4*)(cvals + mt * 16 + g4 * 4);
            f32x4 bf = *(const f32x4*)(bfin + mt * 16 + g4 * 4);
            f32x4 ov;
            #pragma unroll
            for (int r = 0; r < 4; ++r) ov[r] = s * (acc[mt][r] + cv[r]) + bf[r];
            *(f32x4*)(out + (size_t)bidx * SDIM + mt * 16 + g4 * 4) = ov;
        }
    }
}

extern "C" void kernel_launch(void* const* d_in, const int* in_sizes, int n_in,
                              void* d_out, int out_size, void* d_ws, size_t ws_size,
                              hipStream_t stream)
{
    const float* z    = (const float*)d_in[0];
    const float* wq   = (const float*)d_in[1];
    const float* bq   = (const float*)d_in[2];
    const float* wk   = (const float*)d_in[3];
    const float* bk   = (const float*)d_in[4];
    const float* Wf   = (const float*)d_in[5];
    const float* bfin = (const float*)d_in[6];
    const int*   midx = (const int*)d_in[7];
    const int F = in_sizes[1];
    float* out = (float*)d_out;

    if (ws_size >= (size_t)WS_NEED) {
        char* ws = (char*)d_ws;
        float*  c     = (float*)ws;                  // 65 floats
        bf16x8* afrag = (bf16x8*)(ws + 4096);        // 640 KB
        prep_c    <<<65,  64,  0, stream>>>(bq, bk, Wf, F, c);
        prep_afrag<<<160, 256, 0, stream>>>(wq, wk, Wf, midx, F, afrag);
        gemm_wide <<<256, 512, 0, stream>>>(z, afrag, c, bfin, out);
    } else {
        fused_kernel<<<256, 512, 0, stream>>>(z, wq, bq, wk, bk, Wf, bfin, midx, F, out);
    }
}

// Round 17
// 60.071 us; speedup vs baseline: 1.5071x; 1.2330x over previous
//
#include <hip/hip_runtime.h>
#include <hip/hip_bf16.h>

#define LATENT 4096
#define SDIM   64
#define MT     5              // 5 m-tiles of 16 = 80 rows (64 outputs + s_row + pad)
#define CHUNK2 64             // floats of K per staged chunk (= 2 k-steps)
#define NCH2   (LATENT / CHUNK2)  // 64
#define NBUF   4
#define ROWS   64             // batch rows per block
#define WS_NEED (4096 + 655360 + 8192)

typedef __bf16 bf16x8 __attribute__((ext_vector_type(8)));
typedef float  f32x4  __attribute__((ext_vector_type(4)));

#define GLOBAL_AS __attribute__((address_space(1)))
#define LDS_AS    __attribute__((address_space(3)))

__device__ __forceinline__ void load_lds16(const float* g, float* l) {
    __builtin_amdgcn_global_load_lds((const GLOBAL_AS void*)g, (LDS_AS void*)l, 16, 0, 0);
}

#define WAITB(N) do { asm volatile("s_waitcnt vmcnt(" #N ")" ::: "memory"); \
                      __builtin_amdgcn_s_barrier(); } while (0)

// ======================= fused precompute (needs d_ws) =======================
// blocks 0..127 : afrag m-tiles 0..3, idx = ((kstep*4+mt)*64+lane), kstep<=127
// block  128    : wqf packed s-row fragments (128 ksteps x 4 g4 x 16B = 8 KB)
// blocks 129..193: c[o] (o = bid-129; o==64 -> sum bq), 256 thr each, parallel
__global__ __launch_bounds__(256) void prep_fused(
    const float* __restrict__ wq, const float* __restrict__ wk,
    const float* __restrict__ Wf, const int* __restrict__ midx,
    const float* __restrict__ bq, const float* __restrict__ bk,
    int F, bf16x8* __restrict__ afrag, bf16x8* __restrict__ wqf,
    float* __restrict__ c)
{
    __shared__ int inv[LATENT];
    __shared__ float rb[4];
    const int t = threadIdx.x;
    const int bid = blockIdx.x;

    if (bid >= 129) {  // ---- c[o] blocks (coalesced, 65-way parallel) ----
        const int o = bid - 129;
        float p = 0.f;
        if (o < SDIM) { for (int f = t; f < F; f += 256) p += bk[f] * Wf[o * F + f]; }
        else          { for (int f = t; f < F; f += 256) p += bq[f]; }
        #pragma unroll
        for (int off = 32; off; off >>= 1) p += __shfl_down(p, off);
        if ((t & 63) == 0) rb[t >> 6] = p;
        __syncthreads();
        if (t == 0) c[o] = rb[0] + rb[1] + rb[2] + rb[3];
        return;
    }

    // inv[d] = f if mask_idx[f]==d else -1 (afrag + wqf blocks)
    #pragma unroll
    for (int d = t; d < LATENT; d += 256) inv[d] = -1;
    __syncthreads();
    for (int f = t; f < F; f += 256) inv[midx[f]] = f;
    __syncthreads();

    if (bid == 128) {  // ---- wqf: fragment q -> kstep=q>>2, g4=q&3 ----
        for (int q = t; q < 512; q += 256) {
            const int kbase = (q >> 2) * 32 + (q & 3) * 8;   // <= 4088
            bf16x8 v;
            #pragma unroll
            for (int j = 0; j < 8; ++j) {
                int f = inv[kbase + j];
                v[j] = (__bf16)((f >= 0) ? wq[f] : 0.f);
            }
            wqf[q] = v;
        }
        return;
    }

    // ---- afrag m-tiles 0..3: 128 blocks x 256 thr = 32768 fragments ----
    const int g = bid * 256 + t;                 // 0 .. 32767
    const int lane = g & 63;
    const int mt = (g >> 6) & 3;                 // 0..3
    const int ks = g >> 8;                       // 0..127 (bounded by grid)
    const int m = mt * 16 + (lane & 15);
    const int kbase = ks * 32 + (lane >> 4) * 8; // <= 4088
    bf16x8 v;
    #pragma unroll
    for (int j = 0; j < 8; ++j) {
        int f = inv[kbase + j];
        v[j] = (__bf16)((f >= 0) ? wk[f] * Wf[m * F + f] : 0.f);
    }
    afrag[g] = v;
}

struct AF { bf16x8 a0, a1, a2, a3, a4; };

// main: D[80 x 16384] = A[80 x 4096] * z^T — r15 schedule, tile4 via wqf.
// 256 blocks x 512 thr (8 waves): wave = (ks 0..1) x (nq 0..3), 64 rows/block.
// Distance-2 counted-vmcnt ring: 7-op sets (4 afrag + 1 wqf + 2 gload_lds),
// WAITB(14) — ledger identical to r15.
__global__ __launch_bounds__(512, 2) void gemm_wide(
    const float* __restrict__ z, const bf16x8* __restrict__ afrag,
    const bf16x8* __restrict__ wqf,
    const float* __restrict__ c, const float* __restrict__ bfin,
    float* __restrict__ out)
{
    __shared__ __align__(16) float zbuf[NBUF][ROWS][CHUNK2];   // 64 KB
    float (*red)[MT][4][64] = (float (*)[MT][4][64])zbuf;      // [nq][mt][r][lane] 20KB

    const int tid  = threadIdx.x;
    const int lane = tid & 63;
    const int wid  = tid >> 6;     // 0..7
    const int ks   = wid >> 2;     // k-step within chunk (0..1)
    const int nq   = wid & 3;      // row quarter (16 rows)
    const int col  = lane & 15;
    const int g4   = lane >> 4;
    const int r0   = blockIdx.x * ROWS;

    // staging: wave stages rows 8*wid..8*wid+7 via 2 gload_lds (4 rows each).
    // Pre-swizzled global source so linear LDS pos p holds z col (p ^ ((row&7)<<2)).
    const int lrow0 = 8 * wid + (lane >> 4);
    const int lrow1 = lrow0 + 4;
    const int cslot = (lane & 15) * 4;
    const float* zsrc0 = z + (size_t)(r0 + lrow0) * LATENT + (cslot ^ ((lrow0 & 7) << 2));
    const float* zsrc1 = z + (size_t)(r0 + lrow1) * LATENT + (cslot ^ ((lrow1 & 7) << 2));

    f32x4 acc[MT] = {};

    auto stage = [&](int cN) {   // 2 VMEM ops (8 LDS rows of 256B)
        float* d = &zbuf[cN & 3][8 * wid][0];
        load_lds16(zsrc0 + cN * CHUNK2, d);
        load_lds16(zsrc1 + cN * CHUNK2, d + 256);
    };
    auto loadA = [&](int cN, AF& Fr) {   // 5 VMEM ops (4x1KB + 1x16B)
        const int kstep = cN * 2 + ks;
        const bf16x8* p = afrag + (size_t)(kstep * 4) * 64 + lane;
        Fr.a0 = p[0]; Fr.a1 = p[64]; Fr.a2 = p[128]; Fr.a3 = p[192];
        Fr.a4 = wqf[kstep * 4 + g4];               // 64B unique, L1-broadcast
    };
    auto consume = [&](int cN, const AF& Fr) {
        const int q = cN & 3;
        const int base = ks * 32 + g4 * 8;         // multiple of 8
        const int b0 = base ^ ((col & 7) << 2);    // 16B-aligned
        const float* pr = &zbuf[q][nq * 16 + col][0];
        f32x4 a = *(const f32x4*)(pr + b0);
        f32x4 b = *(const f32x4*)(pr + (b0 ^ 4));
        bf16x8 bv;
        bv[0] = (__bf16)a[0]; bv[1] = (__bf16)a[1];
        bv[2] = (__bf16)a[2]; bv[3] = (__bf16)a[3];
        bv[4] = (__bf16)b[0]; bv[5] = (__bf16)b[1];
        bv[6] = (__bf16)b[2]; bv[7] = (__bf16)b[3];
        bf16x8 zv{};
        bf16x8 a4 = (col == 0) ? Fr.a4 : zv;       // rows 65..79 were zeros anyway
        acc[0] = __builtin_amdgcn_mfma_f32_16x16x32_bf16(Fr.a0, bv, acc[0], 0, 0, 0);
        acc[1] = __builtin_amdgcn_mfma_f32_16x16x32_bf16(Fr.a1, bv, acc[1], 0, 0, 0);
        acc[2] = __builtin_amdgcn_mfma_f32_16x16x32_bf16(Fr.a2, bv, acc[2], 0, 0, 0);
        acc[3] = __builtin_amdgcn_mfma_f32_16x16x32_bf16(Fr.a3, bv, acc[3], 0, 0, 0);
        acc[4] = __builtin_amdgcn_mfma_f32_16x16x32_bf16(a4,    bv, acc[4], 0, 0, 0);
    };

    AF f_a, f_b, f_c;
    // ledger: prologue sets 0,1 in flight -> 14 outstanding VMEM ops
    loadA(0, f_a); stage(0);
    loadA(1, f_b); stage(1);

    // steady state: issue set h+2 (+7 -> 21), WAITB(14) retires set h, consume h.
    for (int hb = 0; hb < NCH2 - 4; hb += 3) {
        loadA(hb + 2, f_c); stage(hb + 2);
        WAITB(14); consume(hb,     f_a);
        loadA(hb + 3, f_a); stage(hb + 3);
        WAITB(14); consume(hb + 1, f_b);
        loadA(hb + 4, f_b); stage(hb + 4);
        WAITB(14); consume(hb + 2, f_c);
    }
    // tail: outstanding = sets {60,61}
    loadA(62, f_c); stage(62); WAITB(14); consume(60, f_a);
    loadA(63, f_a); stage(63); WAITB(14); consume(61, f_b);
    WAITB(7); consume(62, f_c);
    WAITB(0); consume(63, f_a);

    // ---- 2-way reduce (ks=1 -> ks=0) per nq; then epilogue by ks=0 waves ----
    __syncthreads();
    if (ks == 1) {
        #pragma unroll
        for (int mt = 0; mt < MT; ++mt)
            #pragma unroll
            for (int r = 0; r < 4; ++r) red[nq][mt][r][lane] = acc[mt][r];
    }
    __syncthreads();
    if (ks == 0) {
        #pragma unroll
        for (int mt = 0; mt < MT; ++mt)
            #pragma unroll
            for (int r = 0; r < 4; ++r) acc[mt][r] += red[nq][mt][r][lane];

        // s-row (m=64) lives in acc[4][0] of lanes 0-15; broadcast via shuffle
        const float s = __shfl(acc[4][0], col) + c[SDIM];
        const int b = r0 + nq * 16 + col;
        #pragma unroll
        for (int mt = 0; mt < 4; ++mt) {
            f32x4 cv = *(const f32x4*)(c    + mt * 16 + g4 * 4);
            f32x4 bf = *(const f32x4*)(bfin + mt * 16 + g4 * 4);
            f32x4 ov;
            #pragma unroll
            for (int r = 0; r < 4; ++r) ov[r] = s * (acc[mt][r] + cv[r]) + bf[r];
            *(f32x4*)(out + (size_t)b * SDIM + mt * 16 + g4 * 4) = ov;
        }
    }
}

// ================== fused fallback (round-2 kernel, verbatim) ==================
#define BK     128
#define NCH    (LATENT / BK)

__global__ __launch_bounds__(512, 2) void fused_kernel(
    const float* __restrict__ z,
    const float* __restrict__ wq, const float* __restrict__ bq,
    const float* __restrict__ wk, const float* __restrict__ bk,
    const float* __restrict__ Wf, const float* __restrict__ bfin,
    const int* __restrict__ midx, int F,
    float* __restrict__ out)
{
    __shared__ __align__(16) unsigned char ubuf[2 * 80 * BK * 2];
    __shared__ int   inv[LATENT];
    __shared__ float cvals[68];
    __shared__ float srow[4][16];

    __bf16* Ab = (__bf16*)ubuf;
    float (*red)[MT][4][64] = (float (*)[MT][4][64])ubuf;

    const int tid  = threadIdx.x;
    const int lane = tid & 63;
    const int w    = tid >> 6;
    const int rg   = w & 3;
    const int kh   = w >> 2;
    const int r0   = blockIdx.x * 64 + rg * 16;
    const int col  = lane & 15;
    const int g4   = lane >> 4;

    for (int d = tid; d < LATENT; d += 512) inv[d] = -1;
    __syncthreads();
    for (int f = tid; f < F; f += 512) inv[midx[f]] = f;
    {
        const int o = tid >> 3, fo = tid & 7;
        float p = 0.f;
        for (int f = fo; f < F; f += 8) p += bk[f] * Wf[o * F + f];
        p += __shfl_xor(p, 1); p += __shfl_xor(p, 2); p += __shfl_xor(p, 4);
        if (fo == 0) cvals[o] = p;
    }
    if (w == 0) {
        float q = 0.f;
        for (int f = lane; f < F; f += 64) q += bq[f];
        #pragma unroll
        for (int off = 32; off; off >>= 1) q += __shfl_down(q, off);
        if (lane == 0) cvals[64] = q;
    }
    __syncthreads();

    f32x4 acc[MT] = {};

    auto build = [&](int ch, int b) {
        const int k  = tid & 127;
        const int mb = tid >> 7;
        const int f  = inv[ch * BK + k];
        const float wkf = (f >= 0) ? wk[f] : 0.f;
        const float wqf2 = (f >= 0) ? wq[f] : 0.f;
        __bf16* dst = Ab + b * 80 * BK;
        #pragma unroll
        for (int i = 0; i < 20; ++i) {
            const int m = mb + 4 * i;
            float x = 0.f;
            if (m < SDIM) { if (f >= 0) x = wkf * Wf[m * F + f]; }
            else if (m == SDIM) x = wqf2;
            dst[m * BK + (k ^ ((m & 7) << 3))] = (__bf16)x;
        }
    };

    auto compute = [&](int ch, int b) {
        const float* zp = z + (size_t)(r0 + col) * LATENT + ch * BK + kh * 64 + g4 * 8;
        f32x4 za0 = *(const f32x4*)(zp);
        f32x4 za1 = *(const f32x4*)(zp + 4);
        f32x4 zb0 = *(const f32x4*)(zp + 32);
        f32x4 zb1 = *(const f32x4*)(zp + 36);
        const __bf16* src = Ab + b * 80 * BK;
        const int kl0 = kh * 64 + g4 * 8;
        bf16x8 bv;
        bv[0] = (__bf16)za0[0]; bv[1] = (__bf16)za0[1];
        bv[2] = (__bf16)za0[2]; bv[3] = (__bf16)za0[3];
        bv[4] = (__bf16)za1[0]; bv[5] = (__bf16)za1[1];
        bv[6] = (__bf16)za1[2]; bv[7] = (__bf16)za1[3];
        #pragma unroll
        for (int mt = 0; mt < MT; ++mt) {
            const int m = mt * 16 + col;
            bf16x8 av = *(const bf16x8*)(src + m * BK + (kl0 ^ ((m & 7) << 3)));
            acc[mt] = __builtin_amdgcn_mfma_f32_16x16x32_bf16(av, bv, acc[mt], 0, 0, 0);
        }
        const int kl1 = kl0 + 32;
        bv[0] = (__bf16)zb0[0]; bv[1] = (__bf16)zb0[1];
        bv[2] = (__bf16)zb0[2]; bv[3] = (__bf16)zb0[3];
        bv[4] = (__bf16)zb1[0]; bv[5] = (__bf16)zb1[1];
        bv[6] = (__bf16)zb1[2]; bv[7] = (__bf16)zb1[3];
        #pragma unroll
        for (int mt = 0; mt < MT; ++mt) {
            const int m = mt * 16 + col;
            bf16x8 av = *(const bf16x8*)(src + m * BK + (kl1 ^ ((m & 7) << 3)));
            acc[mt] = __builtin_amdgcn_mfma_f32_16x16x32_bf16(av, bv, acc[mt], 0, 0, 0);
        }
    };

    build(0, 0);
    __syncthreads();
    #pragma unroll 2
    for (int ch = 0; ch < NCH; ++ch) {
        const int b = ch & 1;
        if (ch + 1 < NCH) build(ch + 1, b ^ 1);
        compute(ch, b);
        __syncthreads();
    }

    if (kh == 1) {
        #pragma unroll
        for (int mt = 0; mt < MT; ++mt)
            #pragma unroll
            for (int r = 0; r < 4; ++r) red[rg][mt][r][lane] = acc[mt][r];
    }
    __syncthreads();
    if (kh == 0) {
        #pragma unroll
        for (int mt = 0; mt < MT; ++mt)
            #pragma unroll
            for (int r = 0; r < 4; ++r) acc[mt][r] += red[rg][mt][r][lane];
        if (g4 == 0) srow[rg][col] = acc[4][0];
    }
    __syncthreads();

    if (kh == 0) {
        const float s = srow[rg][col] + cvals[64];
        const int bidx = r0 + col;
        #pragma unroll
        for (int mt = 0; mt < 4; ++mt) {
            f32x4 cv = *(const f32x4*)(cvals + mt * 16 + g4 * 4);
            f32x4 bf = *(const f32x4*)(bfin + mt * 16 + g4 * 4);
            f32x4 ov;
            #pragma unroll
            for (int r = 0; r < 4; ++r) ov[r] = s * (acc[mt][r] + cv[r]) + bf[r];
            *(f32x4*)(out + (size_t)bidx * SDIM + mt * 16 + g4 * 4) = ov;
        }
    }
}

extern "C" void kernel_launch(void* const* d_in, const int* in_sizes, int n_in,
                              void* d_out, int out_size, void* d_ws, size_t ws_size,
                              hipStream_t stream)
{
    const float* z    = (const float*)d_in[0];
    const float* wq   = (const float*)d_in[1];
    const float* bq   = (const float*)d_in[2];
    const float* wk   = (const float*)d_in[3];
    const float* bk   = (const float*)d_in[4];
    const float* Wf   = (const float*)d_in[5];
    const float* bfin = (const float*)d_in[6];
    const int*   midx = (const int*)d_in[7];
    const int F = in_sizes[1];
    float* out = (float*)d_out;

    if (ws_size >= (size_t)WS_NEED) {
        char* ws = (char*)d_ws;
        float*  c     = (float*)ws;                       // 65 floats
        bf16x8* afrag = (bf16x8*)(ws + 4096);             // 512 KB used
        bf16x8* wqf   = (bf16x8*)(ws + 4096 + 655360);    // 8 KB
        prep_fused<<<194, 256, 0, stream>>>(wq, wk, Wf, midx, bq, bk, F, afrag, wqf, c);
        gemm_wide <<<256, 512, 0, stream>>>(z, afrag, wqf, c, bfin, out);
    } else {
        fused_kernel<<<256, 512, 0, stream>>>(z, wq, bq, wk, bk, Wf, bfin, midx, F, out);
    }
}